// Round 3
// baseline (18720.711 us; speedup 1.0000x reference)
//
#include <hip/hip_runtime.h>
#include <cstdint>
#include <cstddef>

#define TT 128   // T
#define NBATCH 16
#define HH 1024
#define G4 4096  // 4*H

// ---------------- embedding gather ----------------
__global__ __launch_bounds__(256) void embed_kernel(const int* __restrict__ y,
    const float* __restrict__ embed, float* __restrict__ emb) {
  int idx = blockIdx.x * 256 + threadIdx.x;   // float4 index over [2048][128]
  int n = idx >> 7, c = idx & 127;
  int tok = y[n];
  reinterpret_cast<float4*>(emb)[idx] =
      reinterpret_cast<const float4*>(embed)[(size_t)tok * 128 + c];
}

// ---------------- generic fp32 GEMM: C[M,N] = A[M,K] * W[N,K]^T + b1 + b2, opt tanh
__global__ __launch_bounds__(256) void gemm_fp32(
    const float* __restrict__ A, const float* __restrict__ W,
    const float* __restrict__ b1, const float* __restrict__ b2,
    float* __restrict__ C, int M, int N, int K, int act) {
  __shared__ float As[16][132];
  __shared__ float Ws[16][132];
  const int tid = threadIdx.x;
  const int m0 = blockIdx.y * 128, n0 = blockIdx.x * 128;
  const int ty = tid >> 4, tx = tid & 15;
  const int lm = tid >> 1;            // 0..127
  const int lk = (tid & 1) * 8;       // 0 or 8
  float acc[8][8];
#pragma unroll
  for (int i = 0; i < 8; ++i)
#pragma unroll
    for (int j = 0; j < 8; ++j) acc[i][j] = 0.f;

  for (int k0 = 0; k0 < K; k0 += 16) {
    float4 a0 = *reinterpret_cast<const float4*>(A + (size_t)(m0 + lm) * K + k0 + lk);
    float4 a1 = *reinterpret_cast<const float4*>(A + (size_t)(m0 + lm) * K + k0 + lk + 4);
    float4 w0 = *reinterpret_cast<const float4*>(W + (size_t)(n0 + lm) * K + k0 + lk);
    float4 w1 = *reinterpret_cast<const float4*>(W + (size_t)(n0 + lm) * K + k0 + lk + 4);
    __syncthreads();
    As[lk + 0][lm] = a0.x; As[lk + 1][lm] = a0.y; As[lk + 2][lm] = a0.z; As[lk + 3][lm] = a0.w;
    As[lk + 4][lm] = a1.x; As[lk + 5][lm] = a1.y; As[lk + 6][lm] = a1.z; As[lk + 7][lm] = a1.w;
    Ws[lk + 0][lm] = w0.x; Ws[lk + 1][lm] = w0.y; Ws[lk + 2][lm] = w0.z; Ws[lk + 3][lm] = w0.w;
    Ws[lk + 4][lm] = w1.x; Ws[lk + 5][lm] = w1.y; Ws[lk + 6][lm] = w1.z; Ws[lk + 7][lm] = w1.w;
    __syncthreads();
#pragma unroll
    for (int kk = 0; kk < 16; ++kk) {
      float4 av0 = *reinterpret_cast<float4*>(&As[kk][ty * 8]);
      float4 av1 = *reinterpret_cast<float4*>(&As[kk][ty * 8 + 4]);
      float4 wv0 = *reinterpret_cast<float4*>(&Ws[kk][tx * 8]);
      float4 wv1 = *reinterpret_cast<float4*>(&Ws[kk][tx * 8 + 4]);
      float a[8] = {av0.x, av0.y, av0.z, av0.w, av1.x, av1.y, av1.z, av1.w};
      float w[8] = {wv0.x, wv0.y, wv0.z, wv0.w, wv1.x, wv1.y, wv1.z, wv1.w};
#pragma unroll
      for (int i = 0; i < 8; ++i)
#pragma unroll
        for (int j = 0; j < 8; ++j) acc[i][j] += a[i] * w[j];
    }
  }
  // epilogue
#pragma unroll
  for (int i = 0; i < 8; ++i) {
    int m = m0 + ty * 8 + i;
#pragma unroll
    for (int j = 0; j < 8; j += 4) {
      int n = n0 + tx * 8 + j;
      float4 o;
      o.x = acc[i][j + 0] + b1[n + 0] + (b2 ? b2[n + 0] : 0.f);
      o.y = acc[i][j + 1] + b1[n + 1] + (b2 ? b2[n + 1] : 0.f);
      o.z = acc[i][j + 2] + b1[n + 2] + (b2 ? b2[n + 2] : 0.f);
      o.w = acc[i][j + 3] + b1[n + 3] + (b2 ? b2[n + 3] : 0.f);
      if (act) { o.x = tanhf(o.x); o.y = tanhf(o.y); o.z = tanhf(o.z); o.w = tanhf(o.w); }
      *reinterpret_cast<float4*>(C + (size_t)m * N + n) = o;
    }
  }
}

// ---------------- grid barrier (spin, agent scope) ----------------
__device__ __forceinline__ void grid_barrier(unsigned* bar, unsigned nblocks) {
  __threadfence();
  __syncthreads();
  if (threadIdx.x == 0) {
    unsigned g = __hip_atomic_load(&bar[1], __ATOMIC_ACQUIRE, __HIP_MEMORY_SCOPE_AGENT);
    unsigned a = __hip_atomic_fetch_add(&bar[0], 1u, __ATOMIC_ACQ_REL, __HIP_MEMORY_SCOPE_AGENT);
    if (a == nblocks - 1) {
      __hip_atomic_store(&bar[0], 0u, __ATOMIC_RELAXED, __HIP_MEMORY_SCOPE_AGENT);
      __hip_atomic_fetch_add(&bar[1], 1u, __ATOMIC_RELEASE, __HIP_MEMORY_SCOPE_AGENT);
    } else {
      while (__hip_atomic_load(&bar[1], __ATOMIC_ACQUIRE, __HIP_MEMORY_SCOPE_AGENT) == g) {
        __builtin_amdgcn_s_sleep(2);
      }
    }
  }
  __syncthreads();
  __threadfence();
}

// ---------------- LSTM layer: persistent, 256 blocks, W_hh in registers ----------
// Block bid owns h columns j = bid*4 .. bid*4+3 (16 gate rows).
// Thread (r = tid>>4, ks = tid&15): gate row r, K-slice {ks*4 + 64*m + e}.
// h state double-buffered across steps: read cur, write nxt, one grid barrier, swap.
__global__ __launch_bounds__(256) void lstm_kernel(
    const float* __restrict__ xg,    // [B*T, 4H], includes b_ih + b_hh
    const float* __restrict__ W_hh,  // [4H, H]
    const float* __restrict__ h0,    // [B,H] (layer slice)
    const float* __restrict__ c0,    // [B,H]
    float* __restrict__ hbuf0,       // [B,H] state buffer (even steps read)
    float* __restrict__ hbuf1,       // [B,H] state buffer (odd steps read)
    float* __restrict__ hs,          // [B*T, H] layer output
    unsigned* __restrict__ bar) {
  __shared__ float4 lds_h[16 * 256];                       // 64 KB: h[b][256 f4]
  float* lds_g = reinterpret_cast<float*>(lds_h);          // aliased gates [16][17]

  const int tid = threadIdx.x;
  const int bid = blockIdx.x;
  const int r = tid >> 4;          // 0..15
  const int ks = tid & 15;         // 0..15
  const int gate = r >> 2, jj = r & 3;
  const int grow = gate * HH + bid * 4 + jj;   // row in W_hh / column in xg

  // persistent W_hh fragment: 64 floats, k = ks*4 + 64*m + e
  float4 wreg[16];
#pragma unroll
  for (int m = 0; m < 16; ++m)
    wreg[m] = *reinterpret_cast<const float4*>(W_hh + (size_t)grow * HH + ks * 4 + 64 * m);

  // init c (held by consumer threads) and our slice of the step-0 read buffer
  float c_reg = 0.f;
  if (tid < 64) {
    int b = tid & 15, jl = tid >> 4;
    int j = bid * 4 + jl;
    c_reg = c0[b * HH + j];
    hbuf0[b * HH + j] = h0[b * HH + j];
  }
  grid_barrier(bar, gridDim.x);

  float* cur = hbuf0;
  float* nxt = hbuf1;
  for (int t = 0; t < TT; ++t) {
    // prefetch this thread's xg value (b = ks)
    float xgv = xg[(size_t)(ks * TT + t) * G4 + grow];
    // stage h -> LDS (read buffer)
    const float4* hg4 = reinterpret_cast<const float4*>(cur);
#pragma unroll
    for (int i = 0; i < 16; ++i) {
      int idx = i * 256 + tid;         // 0..4095
      lds_h[idx] = hg4[idx];
    }
    __syncthreads();
    // partial dots for all 16 batches over this thread's K slice
    float acc[16];
#pragma unroll
    for (int b = 0; b < 16; ++b) {
      float fa = 0.f;
#pragma unroll
      for (int m = 0; m < 16; ++m) {
        float4 hv = lds_h[b * 256 + m * 16 + ks];
        fa += wreg[m].x * hv.x + wreg[m].y * hv.y + wreg[m].z * hv.z + wreg[m].w * hv.w;
      }
      acc[b] = fa;
    }
    // butterfly reduce across the 16 ks lanes (lane = (r&3)*16 + ks; masks flip ks only)
#pragma unroll
    for (int b = 0; b < 16; ++b) {
      float v = acc[b];
      v += __shfl_xor(v, 1);
      v += __shfl_xor(v, 2);
      v += __shfl_xor(v, 4);
      v += __shfl_xor(v, 8);
      acc[b] = v;
    }
    // this thread publishes gate value for b == ks
    float gv = acc[0];
#pragma unroll
    for (int b = 1; b < 16; ++b) if (ks == b) gv = acc[b];
    gv += xgv;
    __syncthreads();                // all lds_h reads done before aliasing as lds_g
    lds_g[r * 17 + ks] = gv;
    __syncthreads();
    if (tid < 64) {
      int b = tid & 15, jl = tid >> 4;
      float gi = lds_g[(0 * 4 + jl) * 17 + b];
      float gf = lds_g[(1 * 4 + jl) * 17 + b];
      float gg = lds_g[(2 * 4 + jl) * 17 + b];
      float go = lds_g[(3 * 4 + jl) * 17 + b];
      float si = 1.f / (1.f + expf(-gi));
      float sf = 1.f / (1.f + expf(-gf));
      float so = 1.f / (1.f + expf(-go));
      c_reg = sf * c_reg + si * tanhf(gg);
      float hv = so * tanhf(c_reg);
      int j = bid * 4 + jl;
      nxt[b * HH + j] = hv;                      // write buffer (no race with readers of cur)
      hs[(size_t)(b * TT + t) * HH + j] = hv;
    }
    grid_barrier(bar, gridDim.x);
    float* tmp = cur; cur = nxt; nxt = tmp;
  }
}

// ---------------- attention + concat: per (b,t) block ----------------
// mask is int32 (harness ships integer/bool inputs as int32)
__global__ __launch_bounds__(256) void attn_kernel(
    const float* __restrict__ hs1, const float* __restrict__ enc,
    const int* __restrict__ mask, float* __restrict__ cat) {
  __shared__ float4 q4[256];
  __shared__ float sc[128];
  __shared__ float red[8];
  const int tid = threadIdx.x;
  const int n = blockIdx.x;          // b*T + t
  const int b = n >> 7;

  float4 qv = reinterpret_cast<const float4*>(hs1)[(size_t)n * 256 + tid];
  q4[tid] = qv;
  reinterpret_cast<float4*>(cat)[(size_t)n * 512 + tid] = qv;   // cat first half
  __syncthreads();

  // scores: 2 threads per s (k-split halves)
  const int s = tid >> 1, half = tid & 1;
  const float4* e4 = reinterpret_cast<const float4*>(enc) + ((size_t)(b * 128 + s)) * 256 + half * 128;
  const float4* qq = q4 + half * 128;
  float p = 0.f;
#pragma unroll 8
  for (int k = 0; k < 128; ++k) {
    float4 ev = e4[k]; float4 qk = qq[k];
    p += ev.x * qk.x + ev.y * qk.y + ev.z * qk.z + ev.w * qk.w;
  }
  p += __shfl_xor(p, 1);
  if (half == 0) sc[s] = (mask[b * 128 + s] != 0) ? p : -1.0e9f;
  __syncthreads();

  // softmax over 128 scores
  const int lane = tid & 63;
  float v = (tid < 128) ? sc[tid] : -3.4e38f;
#pragma unroll
  for (int off = 32; off; off >>= 1) v = fmaxf(v, __shfl_xor(v, off));
  if (tid < 128 && lane == 0) red[tid >> 6] = v;
  __syncthreads();
  float mx = fmaxf(red[0], red[1]);
  float e = (tid < 128) ? expf(sc[tid] - mx) : 0.f;
  float sum = e;
#pragma unroll
  for (int off = 32; off; off >>= 1) sum += __shfl_xor(sum, off);
  if (lane == 0) red[4 + (tid >> 6)] = sum;
  __syncthreads();
  float tot = red[4] + red[5] + red[6] + red[7];
  if (tid < 128) sc[tid] = e / tot;
  __syncthreads();

  // ctx: each thread owns 4 h channels
  float4 accv = {0.f, 0.f, 0.f, 0.f};
  const float4* eb = reinterpret_cast<const float4*>(enc) + (size_t)b * 128 * 256;
#pragma unroll 4
  for (int ss = 0; ss < 128; ++ss) {
    float a = sc[ss];
    float4 ev = eb[(size_t)ss * 256 + tid];
    accv.x += a * ev.x; accv.y += a * ev.y; accv.z += a * ev.z; accv.w += a * ev.w;
  }
  reinterpret_cast<float4*>(cat)[(size_t)n * 512 + 256 + tid] = accv;
}

// ---------------- launch ----------------
extern "C" void kernel_launch(void* const* d_in, const int* in_sizes, int n_in,
                              void* d_out, int out_size, void* d_ws, size_t ws_size,
                              hipStream_t stream) {
  const int* y_in = (const int*)d_in[0];
  const float* h0 = (const float*)d_in[1];
  const float* c0 = (const float*)d_in[2];
  const float* enc = (const float*)d_in[3];
  const int* mask = (const int*)d_in[4];
  const float* embed = (const float*)d_in[5];
  const float* W_ih0 = (const float*)d_in[6];
  const float* W_hh0 = (const float*)d_in[7];
  const float* b_ih0 = (const float*)d_in[8];
  const float* b_hh0 = (const float*)d_in[9];
  const float* W_ih1 = (const float*)d_in[10];
  const float* W_hh1 = (const float*)d_in[11];
  const float* b_ih1 = (const float*)d_in[12];
  const float* b_hh1 = (const float*)d_in[13];
  const float* fc_W = (const float*)d_in[14];
  const float* fc_b = (const float*)d_in[15];
  const float* out_W = (const float*)d_in[16];
  const float* out_b = (const float*)d_in[17];
  float* out = (float*)d_out;

  float* ws = (float*)d_ws;
  float* emb   = ws;                    // 2048*512          = 1,048,576
  float* xg    = emb + 1048576;         // 2048*4096         = 8,388,608
  float* hs0   = xg + 8388608;          // 2048*1024         = 2,097,152
  float* hs1   = hs0 + 2097152;         // 2048*1024         = 2,097,152
  float* hglob0 = hs1 + 2097152;        // 16*1024           = 16,384
  float* hglob1 = hglob0 + 16384;       // 16*1024           = 16,384
  unsigned* bar = (unsigned*)(hglob1 + 16384);
  float* cat = xg;                      // reuse xg region after LSTM1 (16 MB)
  float* h_t = xg + 4194304;            // next 8 MB of xg region

  hipMemsetAsync(bar, 0, 2 * sizeof(unsigned), stream);
  embed_kernel<<<1024, 256, 0, stream>>>(y_in, embed, emb);
  // xg0 = emb @ W_ih0^T + b_ih0 + b_hh0
  gemm_fp32<<<dim3(32, 16), 256, 0, stream>>>(emb, W_ih0, b_ih0, b_hh0, xg, 2048, 4096, 512, 0);
  lstm_kernel<<<256, 256, 0, stream>>>(xg, W_hh0, h0, c0, hglob0, hglob1, hs0, bar);
  // xg1 = hs0 @ W_ih1^T + b_ih1 + b_hh1
  gemm_fp32<<<dim3(32, 16), 256, 0, stream>>>(hs0, W_ih1, b_ih1, b_hh1, xg, 2048, 4096, 1024, 0);
  lstm_kernel<<<256, 256, 0, stream>>>(xg, W_hh1, h0 + 16384, c0 + 16384, hglob0, hglob1, hs1, bar);
  attn_kernel<<<2048, 256, 0, stream>>>(hs1, enc, mask, cat);
  // h_t = tanh(cat @ fc_W^T + fc_b)
  gemm_fp32<<<dim3(8, 16), 256, 0, stream>>>(cat, fc_W, fc_b, nullptr, h_t, 2048, 1024, 2048, 1);
  // logits = h_t @ out_W^T + out_b
  gemm_fp32<<<dim3(250, 16), 256, 0, stream>>>(h_t, out_W, out_b, nullptr, out, 2048, 32000, 1024, 0);
}